// Round 4
// baseline (668.407 us; speedup 1.0000x reference)
//
#include <hip/hip_runtime.h>

#define NLEV 8
#define NBIG 5    // levels 3..7: 4MB tables, 19-bit hash space each
#define COLS 43   // 8*(2+3)+3
#define TPB1 256  // K1 gather kernel
#define TPB  64   // K2 assemble / fallback kernel

typedef float v4f __attribute__((ext_vector_type(4)));
typedef float v2f __attribute__((ext_vector_type(2)));

// per-level cumulative start offsets and pow2 size masks
// sizes: 4096, 32768, 262144, 524288 x5  (all pow2 -> mod == and)
__device__ __constant__ unsigned off_c[NLEV]  = {0u, 4096u, 36864u, 299008u,
                                                 823296u, 1347584u, 1871872u, 2396160u};
__device__ __constant__ unsigned mask_c[NLEV] = {4095u, 32767u, 262143u, 524287u,
                                                 524287u, 524287u, 524287u, 524287u};

// ---------------- K1: hash-slice-partitioned gather for big levels ----------------
// All 5 big levels have 19-bit tables -> id>>16 gives 8 slices of 512KB.
// partition p = blockIdx&7 -> XCD p (dispatch round-robins XCDs). Each block
// computes hashes for ALL big levels but gathers only ids in its slice
// (predicated, ~1/8 lanes). Per-XCD table working set = 5*512KB = 2.5MB
// -> L2-resident (round 3's level-per-XCD put 4MB into a 4MB L2 and thrashed).
// Feats written to ws[5][N] by the owning partition only (disjoint 8B regions).
__global__ __launch_bounds__(TPB1) void gather_big(
    const float* __restrict__ inputs,   // [N,3]
    const float2* __restrict__ emb,     // [2920448,2]
    v2f* __restrict__ ws,               // [5][N] feats for levels 3..7
    int N)
{
    const unsigned p = (unsigned)blockIdx.x & 7u;            // slice == XCD
    const int i = (int)((unsigned)blockIdx.x >> 3) * TPB1 + (int)threadIdx.x;
    if (i >= N) return;

    const float x0 = __builtin_nontemporal_load(&inputs[3 * i + 0]);
    const float x1 = __builtin_nontemporal_load(&inputs[3 * i + 1]);
    const float x2 = __builtin_nontemporal_load(&inputs[3 * i + 2]);

    unsigned idw[NBIG];
    bool own[NBIG];
    #pragma unroll
    for (int k = 0; k < NBIG; ++k) {
        const int L = k + 3;
        const float res = (float)(16 << L);
        const float a = x0 * res, b = x1 * res, c = x2 * res;
        const float fa = floorf(a), fb = floorf(b), fc = floorf(c);
        const float ga = a - fa, gb = b - fb, gc = c - fc;
        const unsigned na = (unsigned)fa + (ga < 0.5f ? 0u : 1u);
        const unsigned nb = (unsigned)fb + (gb < 0.5f ? 0u : 1u);
        const unsigned nc = (unsigned)fc + (gc < 0.5f ? 0u : 1u);
        const unsigned h = na ^ (nb * 2654435761u) ^ (nc * 805459861u);
        idw[k] = h & 524287u;             // all big levels: 19-bit mask
        own[k] = (idw[k] >> 16) == p;     // 3 slice bits exactly
    }
    // masked gathers clustered for MLP; only owned lines hit this XCD's L2
    float2 f[NBIG];
    #pragma unroll
    for (int k = 0; k < NBIG; ++k) {
        if (own[k]) f[k] = emb[idw[k] + off_c[k + 3]];
    }
    #pragma unroll
    for (int k = 0; k < NBIG; ++k) {
        if (own[k]) {
            v2f v; v.x = f[k].x; v.y = f[k].y;
            __builtin_nontemporal_store(v, ws + (size_t)k * N + i);
        }
    }
}

// ---------------- K2: assemble (streams ws, gathers small levels) ----------------
// Levels 0-2 total 2.39MB -> resident in every XCD's L2 (streams are all nt,
// so they don't evict the small tables). Recomputes weights (VALU is ~5% free).
__global__ __launch_bounds__(TPB) void assemble_kernel(
    const float* __restrict__ inputs,   // [N,3]
    const float2* __restrict__ emb,     // [2920448,2]
    const v2f* __restrict__ ws,         // [5][N]
    float* __restrict__ out,            // [N,43]
    int N)
{
    __shared__ __align__(16) float lds[TPB * COLS];   // 11008 B
    const int tid = threadIdx.x;
    const int i = blockIdx.x * TPB + tid;

    if (i < N) {
        // issue all 5 streaming feat loads back-to-back
        v2f fb[NBIG];
        #pragma unroll
        for (int k = 0; k < NBIG; ++k)
            fb[k] = __builtin_nontemporal_load(ws + (size_t)k * N + i);

        const float x0 = inputs[3 * i + 0];
        const float x1 = inputs[3 * i + 1];
        const float x2 = inputs[3 * i + 2];

        // small levels 0-2: direct gathers from L2-resident tables
        float2 fs[3];
        #pragma unroll
        for (int L = 0; L < 3; ++L) {
            const float res = (float)(16 << L);
            const float a = x0 * res, b = x1 * res, c = x2 * res;
            const float fa = floorf(a), fb2 = floorf(b), fc = floorf(c);
            const float ga = a - fa, gb = b - fb2, gc = c - fc;
            const unsigned na = (unsigned)fa + (ga < 0.5f ? 0u : 1u);
            const unsigned nb = (unsigned)fb2 + (gb < 0.5f ? 0u : 1u);
            const unsigned nc = (unsigned)fc + (gc < 0.5f ? 0u : 1u);
            const unsigned h = na ^ (nb * 2654435761u) ^ (nc * 805459861u);
            fs[L] = emb[(h & mask_c[L]) + off_c[L]];
        }

        float* row = &lds[tid * COLS];   // stride 43: odd -> 2-way bank alias (free)
        #pragma unroll
        for (int L = 0; L < NLEV; ++L) {
            const float res = (float)(16 << L);
            const float a = x0 * res, b = x1 * res, c = x2 * res;
            const float ga = a - floorf(a), gb = b - floorf(b), gc = c - floorf(c);
            row[5 * L + 2] = ga < 0.5f ? ga : 1.0f - ga;
            row[5 * L + 3] = gb < 0.5f ? gb : 1.0f - gb;
            row[5 * L + 4] = gc < 0.5f ? gc : 1.0f - gc;
        }
        #pragma unroll
        for (int L = 0; L < 3; ++L) {
            row[5 * L + 0] = fs[L].x;
            row[5 * L + 1] = fs[L].y;
        }
        #pragma unroll
        for (int k = 0; k < NBIG; ++k) {
            row[5 * (k + 3) + 0] = fb[k].x;
            row[5 * (k + 3) + 1] = fb[k].y;
        }
        row[40] = x0;
        row[41] = x1;
        row[42] = x2;
    }
    __syncthreads();   // single-wave block: wave-local, just orders LDS

    const long long tile_base = (long long)blockIdx.x * (TPB * COLS);
    if ((blockIdx.x + 1) * TPB <= N) {
        v4f* __restrict__ out4 = (v4f*)(out + tile_base);
        const v4f* l4 = (const v4f*)lds;
        const int NV = TPB * COLS / 4;      // 688
        #pragma unroll
        for (int j = 0; j < 10; ++j) {
            const int k = tid + j * TPB;
            __builtin_nontemporal_store(l4[k], &out4[k]);
        }
        const int k = tid + 10 * TPB;
        if (k < NV)
            __builtin_nontemporal_store(l4[k], &out4[k]);
    } else {
        const int valid = N - blockIdx.x * TPB;
        const int NT = valid * COLS;
        for (int k = tid; k < NT; k += TPB)
            out[tile_base + k] = lds[k];
    }
}

// ---------------- fallback: round-2 single kernel (ws too small) ----------------
__global__ __launch_bounds__(TPB) void hashgrid_kernel(
    const float* __restrict__ inputs,
    const float2* __restrict__ emb,
    float* __restrict__ out,
    int N)
{
    __shared__ __align__(16) float lds[TPB * COLS];
    const int tid = threadIdx.x;
    const int i = blockIdx.x * TPB + tid;

    if (i < N) {
        const float x0 = inputs[3 * i + 0];
        const float x1 = inputs[3 * i + 1];
        const float x2 = inputs[3 * i + 2];

        unsigned id[NLEV];
        float ga[NLEV], gb[NLEV], gc[NLEV];
        bool  ma[NLEV], mb[NLEV], mc[NLEV];
        #pragma unroll
        for (int L = 0; L < NLEV; ++L) {
            const float res = (float)(16 << L);
            const float a = x0 * res, b = x1 * res, c = x2 * res;
            const float fa = floorf(a), fb = floorf(b), fc = floorf(c);
            ga[L] = a - fa; gb[L] = b - fb; gc[L] = c - fc;
            ma[L] = ga[L] < 0.5f; mb[L] = gb[L] < 0.5f; mc[L] = gc[L] < 0.5f;
            const unsigned na = (unsigned)fa + (ma[L] ? 0u : 1u);
            const unsigned nb = (unsigned)fb + (mb[L] ? 0u : 1u);
            const unsigned nc = (unsigned)fc + (mc[L] ? 0u : 1u);
            const unsigned h = na ^ (nb * 2654435761u) ^ (nc * 805459861u);
            id[L] = (h & mask_c[L]) + off_c[L];
        }
        float2 f[NLEV];
        #pragma unroll
        for (int L = 0; L < NLEV; ++L) f[L] = emb[id[L]];

        float* row = &lds[tid * COLS];
        #pragma unroll
        for (int L = 0; L < NLEV; ++L) {
            row[5 * L + 2] = ma[L] ? ga[L] : 1.0f - ga[L];
            row[5 * L + 3] = mb[L] ? gb[L] : 1.0f - gb[L];
            row[5 * L + 4] = mc[L] ? gc[L] : 1.0f - gc[L];
        }
        row[40] = x0;
        row[41] = x1;
        row[42] = x2;
        #pragma unroll
        for (int L = 0; L < NLEV; ++L) {
            row[5 * L + 0] = f[L].x;
            row[5 * L + 1] = f[L].y;
        }
    }
    __syncthreads();

    const long long tile_base = (long long)blockIdx.x * (TPB * COLS);
    if ((blockIdx.x + 1) * TPB <= N) {
        v4f* __restrict__ out4 = (v4f*)(out + tile_base);
        const v4f* l4 = (const v4f*)lds;
        const int NV = TPB * COLS / 4;
        #pragma unroll
        for (int j = 0; j < 10; ++j) {
            const int k = tid + j * TPB;
            __builtin_nontemporal_store(l4[k], &out4[k]);
        }
        const int k = tid + 10 * TPB;
        if (k < NV)
            __builtin_nontemporal_store(l4[k], &out4[k]);
    } else {
        const int valid = N - blockIdx.x * TPB;
        const int NT = valid * COLS;
        for (int k = tid; k < NT; k += TPB)
            out[tile_base + k] = lds[k];
    }
}

extern "C" void kernel_launch(void* const* d_in, const int* in_sizes, int n_in,
                              void* d_out, int out_size, void* d_ws, size_t ws_size,
                              hipStream_t stream) {
    const float*  inputs = (const float*)d_in[0];
    const float2* emb    = (const float2*)d_in[1];
    float* out = (float*)d_out;
    const int N = in_sizes[0] / 3;   // 2097152

    const size_t ws_need = (size_t)NBIG * N * sizeof(float2);  // 84 MB
    if (d_ws != nullptr && ws_size >= ws_need) {
        const int chunks = (N + TPB1 - 1) / TPB1;   // 8192
        gather_big<<<chunks * 8, TPB1, 0, stream>>>(inputs, emb, (v2f*)d_ws, N);
        const int grid2 = (N + TPB - 1) / TPB;
        assemble_kernel<<<grid2, TPB, 0, stream>>>(inputs, emb, (const v2f*)d_ws, out, N);
    } else {
        const int grid = (N + TPB - 1) / TPB;
        hashgrid_kernel<<<grid, TPB, 0, stream>>>(inputs, emb, out, N);
    }
}

// Round 5
// 542.079 us; speedup vs baseline: 1.2330x; 1.2330x over previous
//
#include <hip/hip_runtime.h>

#define NLEV 8
#define COLS 43    // 8*(2+3)+3
#define TPB  256
#define SMS  260   // LDS row stride (!=0 mod 32) to spread writeout read banks

typedef float v4f __attribute__((ext_vector_type(4)));

// One thread = one point. Stage ONLY feats (16 floats) + xyz (3 floats) in LDS
// (19 floats/point vs 43 before): LDS/block 44KB -> 19.3KB, so blocks/CU 3 -> 8,
// occupancy 37% -> ~100%. Weights are recomputed at writeout from xs (VALU was
// 5% busy - free). Tests the latency-bound hypothesis for the 8-way gather.
// LDS layout: sm[kind*SMS + point], kind = 2L+s for feat (s=0,1), 16+axis for x.
__global__ __launch_bounds__(TPB) void hashgrid_kernel(
    const float* __restrict__ inputs,   // [N,3]
    const float2* __restrict__ emb,     // [2920448,2]
    float* __restrict__ out,            // [N,43]
    int N)
{
    __shared__ float sm[19 * SMS];      // 19760 B -> 8 blocks/CU
    const int tid = threadIdx.x;
    const int i = blockIdx.x * TPB + tid;

    // per-level cumulative start offsets and pow2 size masks
    // sizes: 4096, 32768, 262144, 524288 x5  (all pow2 -> mod == and)
    const unsigned off_c[NLEV]  = {0u, 4096u, 36864u, 299008u,
                                   823296u, 1347584u, 1871872u, 2396160u};
    const unsigned mask_c[NLEV] = {4095u, 32767u, 262143u, 524287u,
                                   524287u, 524287u, 524287u, 524287u};

    if (i < N) {
        const float x0 = inputs[3 * i + 0];
        const float x1 = inputs[3 * i + 1];
        const float x2 = inputs[3 * i + 2];

        // ---- compute all 8 hash ids, then issue all 8 gathers back-to-back ----
        unsigned id[NLEV];
        #pragma unroll
        for (int L = 0; L < NLEV; ++L) {
            const float res = (float)(16 << L);
            const float a = x0 * res, b = x1 * res, c = x2 * res;
            const float fa = floorf(a), fb = floorf(b), fc = floorf(c);
            const float ga = a - fa, gb = b - fb, gc = c - fc;
            const unsigned na = (unsigned)fa + (ga < 0.5f ? 0u : 1u);
            const unsigned nb = (unsigned)fb + (gb < 0.5f ? 0u : 1u);
            const unsigned nc = (unsigned)fc + (gc < 0.5f ? 0u : 1u);
            const unsigned h = na ^ (nb * 2654435761u) ^ (nc * 805459861u);
            id[L] = (h & mask_c[L]) + off_c[L];
        }
        float2 f[NLEV];
        #pragma unroll
        for (int L = 0; L < NLEV; ++L) {
            f[L] = emb[id[L]];          // 8 independent 8B gathers in flight
        }

        // ---- stage: conflict-free (consecutive lanes -> consecutive addrs) ----
        sm[16 * SMS + tid] = x0;
        sm[17 * SMS + tid] = x1;
        sm[18 * SMS + tid] = x2;
        #pragma unroll
        for (int L = 0; L < NLEV; ++L) {
            sm[(2 * L + 0) * SMS + tid] = f[L].x;
            sm[(2 * L + 1) * SMS + tid] = f[L].y;
        }
    }
    __syncthreads();

    // ---- writeout: block tile [TPB][43] as coalesced nt float4 ----
    // elem(k): value of flat tile element k (row r = k/43, col c = k%43).
    // c in [5L,5L+1]: feat from LDS. c in [5L+2,5L+4]: weight recomputed from x.
    // c >= 40: passthrough x. Identical float ops to the stage-phase hash ->
    // bit-identical weights.
    auto elem = [&](int k) -> float {
        const unsigned uk = (unsigned)k;
        const unsigned r = uk / 43u;            // magic-mul division
        const unsigned c = uk - 43u * r;
        if (c >= 40u) {
            return sm[(16u + (c - 40u)) * SMS + r];
        }
        const unsigned L = c / 5u;
        const unsigned s = c - 5u * L;
        if (s < 2u) {
            return sm[(2u * L + s) * SMS + r];
        }
        const unsigned axis = s - 2u;
        const float x = sm[(16u + axis) * SMS + r];
        const float res = (float)(16u << L);
        const float a = x * res;
        const float g = a - floorf(a);
        return g < 0.5f ? g : 1.0f - g;
    };

    const long long tile_base = (long long)blockIdx.x * (TPB * COLS);
    if ((blockIdx.x + 1) * TPB <= N) {
        v4f* __restrict__ out4 = (v4f*)(out + tile_base);   // 44032B tile, 16B-aligned
        const int NV = TPB * COLS / 4;          // 2752 = 256*10 + 192
        #pragma unroll
        for (int j = 0; j < 10; ++j) {
            const int k4 = tid + j * TPB;
            v4f v;
            v.x = elem(4 * k4 + 0);
            v.y = elem(4 * k4 + 1);
            v.z = elem(4 * k4 + 2);
            v.w = elem(4 * k4 + 3);
            __builtin_nontemporal_store(v, &out4[k4]);
        }
        const int k4 = tid + 10 * TPB;
        if (k4 < NV) {
            v4f v;
            v.x = elem(4 * k4 + 0);
            v.y = elem(4 * k4 + 1);
            v.z = elem(4 * k4 + 2);
            v.w = elem(4 * k4 + 3);
            __builtin_nontemporal_store(v, &out4[k4]);
        }
    } else {
        // tail block (not hit for N = 2^21, kept for safety)
        const int valid = N - blockIdx.x * TPB;
        const int NT = valid * COLS;
        for (int k = tid; k < NT; k += TPB)
            out[tile_base + k] = elem(k);
    }
}

extern "C" void kernel_launch(void* const* d_in, const int* in_sizes, int n_in,
                              void* d_out, int out_size, void* d_ws, size_t ws_size,
                              hipStream_t stream) {
    const float*  inputs = (const float*)d_in[0];
    const float2* emb    = (const float2*)d_in[1];
    float* out = (float*)d_out;
    const int N = in_sizes[0] / 3;   // 2097152
    const int grid = (N + TPB - 1) / TPB;
    hashgrid_kernel<<<grid, TPB, 0, stream>>>(inputs, emb, out, N);
}